// Round 5
// baseline (274.400 us; speedup 1.0000x reference)
//
#include <hip/hip_runtime.h>

// out[i]        = p[i]                      i in [0, SIZE)
// out[SIZE + i] = w[i] * selu(p[i]) + q[i]
//
// Round-5: persistent grid-stride kernel, 2048 blocks x 256 = 8 blocks/CU
// = 32 waves/CU (100% occupancy), two phases inside one dispatch:
//   phase 1: copy p -> out[0:SIZE]          (2 streams device-wide)
//   phase 2: out[SIZE:] = w*selu(p) + q     (4 streams; p L3-warm)
// Theory: read BW = in-flight bytes / latency; short-lived blocks never keep
// the read queue full (the harness's own fill kernel hits 6.8 TB/s at 9%
// occupancy because stores are fire-and-forget; reads are not).

typedef float v4f __attribute__((ext_vector_type(4)));

__global__ void __launch_bounds__(256)
activation_moduleA_48112223650431_kernel(const v4f* __restrict__ x4,
                                         const v4f* __restrict__ w4,
                                         v4f* __restrict__ out4,
                                         int n4 /* = SIZE/4 */) {
    const int stride = gridDim.x * blockDim.x;   // 524288
    const int tid0 = blockIdx.x * blockDim.x + threadIdx.x;

    // ---- Phase 1: copy first half (unroll x4: 4 loads in flight) ----
    int i = tid0;
    for (; i + 3 * stride < n4; i += 4 * stride) {
        v4f a0 = x4[i];
        v4f a1 = x4[i + stride];
        v4f a2 = x4[i + 2 * stride];
        v4f a3 = x4[i + 3 * stride];
        out4[i] = a0;
        out4[i + stride] = a1;
        out4[i + 2 * stride] = a2;
        out4[i + 3 * stride] = a3;
    }
    for (; i < n4; i += stride) out4[i] = x4[i];

    // ---- Phase 2: residual second half (unroll x2: 6 loads in flight) ----
    const float scale = 1.0507009873554805f;
    const float alpha = 1.6732632423543773f;

    i = tid0;
    for (; i + stride < n4; i += 2 * stride) {
        v4f p0 = x4[i];
        v4f p1 = x4[i + stride];
        v4f q0 = x4[n4 + i];
        v4f q1 = x4[n4 + i + stride];
        v4f w0 = w4[i];
        v4f w1 = w4[i + stride];
        v4f r0, r1;
#pragma unroll
        for (int c = 0; c < 4; ++c) {
            float pv = p0[c];
            float s = pv > 0.f ? pv : alpha * (__expf(pv) - 1.f);
            r0[c] = w0[c] * (scale * s) + q0[c];
        }
#pragma unroll
        for (int c = 0; c < 4; ++c) {
            float pv = p1[c];
            float s = pv > 0.f ? pv : alpha * (__expf(pv) - 1.f);
            r1[c] = w1[c] * (scale * s) + q1[c];
        }
        out4[n4 + i] = r0;
        out4[n4 + i + stride] = r1;
    }
    for (; i < n4; i += stride) {
        v4f p = x4[i];
        v4f q = x4[n4 + i];
        v4f w = w4[i];
        v4f r;
#pragma unroll
        for (int c = 0; c < 4; ++c) {
            float pv = p[c];
            float s = pv > 0.f ? pv : alpha * (__expf(pv) - 1.f);
            r[c] = w[c] * (scale * s) + q[c];
        }
        out4[n4 + i] = r;
    }
}

extern "C" void kernel_launch(void* const* d_in, const int* in_sizes, int n_in,
                              void* d_out, int out_size, void* d_ws, size_t ws_size,
                              hipStream_t stream) {
    const v4f* x4 = (const v4f*)d_in[0];
    const v4f* w4 = (const v4f*)d_in[1];
    v4f* out4 = (v4f*)d_out;

    int size = in_sizes[1];      // SIZE = N/2 = 16777216
    int n4 = size / 4;           // 4194304 float4 per half

    // 2048 blocks x 256 threads = 8 blocks/CU on 256 CUs = 32 waves/CU.
    int block = 256;
    int grid = 2048;
    activation_moduleA_48112223650431_kernel<<<grid, block, 0, stream>>>(x4, w4, out4, n4);
}